// Round 17
// baseline (238.589 us; speedup 1.0000x reference)
//
#include <hip/hip_runtime.h>
#include <hip/hip_bf16.h>

#define M_TOT 32768
#define DDIM  1024
#define ODIM  768
#define LN_EPS 1e-5f

typedef __attribute__((__ext_vector_type__(8))) short bf16x8;
typedef __attribute__((__ext_vector_type__(4))) float f32x4;

__device__ __forceinline__ unsigned short f2bf(float f) {
  union { __hip_bfloat16 h; unsigned short u; } cv;
  cv.h = __float2bfloat16(f);
  return cv.u;
}

__device__ __forceinline__ int pk2(float a, float b) {
  return (int)((unsigned)f2bf(a) | ((unsigned)f2bf(b) << 16));
}

__device__ __forceinline__ float bflo(unsigned u) {
  union { float f; unsigned v; } c; c.v = u << 16; return c.f;
}
__device__ __forceinline__ float bfhi(unsigned u) {
  union { float f; unsigned v; } c; c.v = u & 0xFFFF0000u; return c.f;
}

__device__ __forceinline__ float silu_f(float v) {
  return v / (1.f + __expf(-v));
}

// ========== kernel 1: row stats (mean/rstd) + wconv + wb-pack ==========
// Blocks [0,8192): 4 rows/block, wave-reduce stats -> sm/sr (reads x only;
// no h write -> 128 MB traffic = ~20.5 us, leaves x L3-resident).
// Blocks [8192,8960): W fp32->bf16. Block 8960: pack (lnw,lnb) as bf16 u32.
__global__ __launch_bounds__(256)
void stats_kernel(const float* __restrict__ x, const float* __restrict__ lnw,
                  const float* __restrict__ lnb, float* __restrict__ sm,
                  float* __restrict__ sr, unsigned* __restrict__ wbpk,
                  const float4* __restrict__ Wf, ushort4* __restrict__ Wb)
{
  const int tid = threadIdx.x;
  const int bid = blockIdx.x;
  if (bid >= 8192) {
    if (bid < 8960) {
      const int i = ((bid - 8192) << 8) + tid;
      float4 v = Wf[i];
      ushort4 o;
      o.x = f2bf(v.x); o.y = f2bf(v.y); o.z = f2bf(v.z); o.w = f2bf(v.w);
      Wb[i] = o;
    } else {
#pragma unroll
      for (int q = 0; q < 4; ++q) {
        const int k = (q << 8) + tid;
        wbpk[k] = (unsigned)f2bf(lnw[k]) | ((unsigned)f2bf(lnb[k]) << 16);
      }
    }
    return;
  }
  const int lane = tid & 63;
  const int wid  = tid >> 6;
  const int row  = (bid << 2) + wid;
  const float4* xr = (const float4*)(x + (size_t)row * DDIM);
  float s = 0.f, ss = 0.f;
#pragma unroll
  for (int jj = 0; jj < 4; ++jj) {
    float4 a = xr[lane + 64 * jj];
    s  += a.x + a.y + a.z + a.w;
    ss += a.x * a.x + a.y * a.y + a.z * a.z + a.w * a.w;
  }
#pragma unroll
  for (int off = 1; off < 64; off <<= 1) {
    s  += __shfl_xor(s, off);
    ss += __shfl_xor(ss, off);
  }
  if (lane == 0) {
    const float mean = s * (1.f / 1024.f);
    sm[row] = mean;
    sr[row] = rsqrtf(ss * (1.f / 1024.f) - mean * mean + LN_EPS);
  }
}

// ==== kernel 2: GEMM + rearrange, producer-consumer wave specialization ====
// 384 thr = 6 waves. Waves 0-3: CONSUMERS -- R15's proven free-run loop
// (B via global_load_lds, VMW(0)+1 raw barrier/tile, 48 MFMA, swizzles,
// paired epilogue) with wave C = 64x96 (2M x 2N). Waves 4-5: PRODUCERS --
// per tile load x(t+1) (coalesced 256B row segments), LN+SiLU with row
// stats in regs, pack bf16, ds_write_b64 into the EXACT LDS A-image the
// old DMA produced (chunk ^= row&7), so consumer frag reads are untouched.
// Race ledger: producer writes buf[(t+1)&1] only after tile-t's top
// barrier (that buffer's readers retired via MFMA-forced lgkm waits before
// crossing it); producer lgkmcnt(0) before each barrier publishes A;
// barrier count identical across roles (16 loop + 8 epilogue).
// LDS = 2 x (A 16 KB + B 24 KB) = 81920 B -> 2 blocks/CU.
#define GBM 128
#define GBN 192
#define GBK 64
#define ABY  16384   // 128 rows x 128 B
#define BUFB 40960   // + 192 rows x 128 B

__device__ __forceinline__ void gload16(const void* g, void* l) {
  __builtin_amdgcn_global_load_lds(
      (const __attribute__((address_space(1))) unsigned int*)g,
      (__attribute__((address_space(3))) unsigned int*)l, 16, 0, 0);
}

#define VMW(n) asm volatile("s_waitcnt vmcnt(" #n ")" ::: "memory")

__global__ __launch_bounds__(384, 3)
void gemm_kernel(const float* __restrict__ x,
                 const float* __restrict__ sm, const float* __restrict__ sr,
                 const unsigned* __restrict__ wbpk,
                 const __hip_bfloat16* __restrict__ Wb,
                 const float* __restrict__ bias,
                 float* __restrict__ out)
{
  __shared__ char smem[2 * BUFB];          // 81920 B static
  const int tid  = threadIdx.x;
  const int lane = tid & 63;
  const int w    = tid >> 6;

  // bijective XCD swizzle (1024 % 8 == 0); nt fastest -> same-XCD shares x
  const int wg = blockIdx.x;
  const int sv = ((wg & 7) << 7) + (wg >> 3);
  const int mt = sv >> 2, nt = sv & 3;
  const int m0 = mt << 7, n0 = nt * GBN;

  const int wm = w >> 1, wn = w & 1;       // consumer wave grid (w<4)
  const int lr = lane & 15, lq = lane >> 4;

  f32x4 acc[4][6];
#pragma unroll
  for (int i = 0; i < 4; ++i)
#pragma unroll
    for (int j = 0; j < 6; ++j)
      acc[i][j] = (f32x4){0.f, 0.f, 0.f, 0.f};

  if (w >= 4) {
    // ======================= PRODUCER (waves 4-5) =======================
    const int p  = tid & 127;              // 0..127
    const int rB = p >> 4;                 // row base 0..7
    const int k4 = p & 15;                 // float4 index within 64-k slab
    float mu[16], rs[16];
#pragma unroll
    for (int i = 0; i < 16; ++i) {
      const int r = rB + (i << 3);
      mu[i] = sm[m0 + r];
      rs[i] = sr[m0 + r];
    }
    const float* xb = x + (size_t)(m0 + rB) * DDIM + (k4 << 2);
    float4 xv[16];
    uint4  wbr;
    auto ploadx = [&](int kt) {
#pragma unroll
      for (int i = 0; i < 16; ++i)
        xv[i] = *(const float4*)(xb + (size_t)(i << 3) * DDIM + (kt << 6));
      wbr = *(const uint4*)(wbpk + (kt << 6) + (k4 << 2));
    };
    auto pwrite = [&](int kt) {
      char* dstb = smem + (kt & 1) * BUFB;
      const int kc = k4 >> 1, hv = k4 & 1;
      const float w0 = bflo(wbr.x), b0 = bfhi(wbr.x);
      const float w1 = bflo(wbr.y), b1 = bfhi(wbr.y);
      const float w2 = bflo(wbr.z), b2 = bfhi(wbr.z);
      const float w3 = bflo(wbr.w), b3 = bfhi(wbr.w);
#pragma unroll
      for (int i = 0; i < 16; ++i) {
        const int r = rB + (i << 3);
        float4 xx = xv[i];
        const float h0 = silu_f((xx.x - mu[i]) * rs[i] * w0 + b0);
        const float h1 = silu_f((xx.y - mu[i]) * rs[i] * w1 + b1);
        const float h2 = silu_f((xx.z - mu[i]) * rs[i] * w2 + b2);
        const float h3 = silu_f((xx.w - mu[i]) * rs[i] * w3 + b3);
        int2 pk; pk.x = pk2(h0, h1); pk.y = pk2(h2, h3);
        *(int2*)(dstb + r * 128 + ((kc ^ (r & 7)) << 4) + (hv << 3)) = pk;
      }
    };
    // prologue: A(0) into buf0; x(1) in flight
    ploadx(0);
    VMW(0);
    pwrite(0);
    ploadx(1);
    asm volatile("s_waitcnt lgkmcnt(0)" ::: "memory");
    for (int t = 0; t < 16; ++t) {
      __builtin_amdgcn_s_barrier();        // top-of-tile t (shared)
      asm volatile("" ::: "memory");
      if (t < 15) {
        VMW(0);                            // x(t+1)/wb(t+1) landed
        pwrite(t + 1);                     // buf[(t+1)&1], freed at barrier
        if (t < 14) ploadx(t + 2);
        asm volatile("s_waitcnt lgkmcnt(0)" ::: "memory");
      }
    }
  } else {
    // ======================= CONSUMER (waves 0-3) =======================
    const __hip_bfloat16* bP[6]; int bD[6];
#pragma unroll
    for (int q = 0; q < 6; ++q) {
      int s = (q << 8) + tid;
      int row = s >> 3, chk = s & 7;
      bP[q] = Wb + (size_t)(n0 + row) * DDIM + ((chk ^ (row & 7)) << 3);
      bD[q] = ABY + (s << 4);
    }
    int aRd[8], bRd[12];
#pragma unroll
    for (int kk = 0; kk < 2; ++kk) {
#pragma unroll
      for (int i = 0; i < 4; ++i) {
        int row = wm * 64 + i * 16 + lr;
        aRd[kk * 4 + i] = row * 128 + ((((kk << 2) | lq) ^ (row & 7)) << 4);
      }
#pragma unroll
      for (int j = 0; j < 6; ++j) {
        int row = wn * 96 + j * 16 + lr;
        bRd[kk * 6 + j] = ABY + row * 128 + ((((kk << 2) | lq) ^ (row & 7)) << 4);
      }
    }
    auto stageB = [&](int t) {             // 6 loads/thread
      char* b = smem + (t & 1) * BUFB;
      const int k0 = t << 6;
#pragma unroll
      for (int q = 0; q < 6; ++q) gload16(bP[q] + k0, b + bD[q]);
    };

    stageB(0);
    for (int t = 0; t < 16; ++t) {
      VMW(0);                              // B(t) landed (covered by t-1)
      __builtin_amdgcn_s_barrier();        // top-of-tile t (shared)
      asm volatile("" ::: "memory");

      const char* bb = smem + (t & 1) * BUFB;
      if (t < 15) stageB(t + 1);           // other buffer; readers retired
      bf16x8 af[4], bfq[6];
      // ---- k-half 0: 24 MFMA ----
#pragma unroll
      for (int i = 0; i < 4; ++i) af[i]  = *(const bf16x8*)(bb + aRd[i]);
#pragma unroll
      for (int j = 0; j < 6; ++j) bfq[j] = *(const bf16x8*)(bb + bRd[j]);
      __builtin_amdgcn_s_setprio(1);
#pragma unroll
      for (int i = 0; i < 4; ++i)
#pragma unroll
        for (int j = 0; j < 6; ++j)
          acc[i][j] = __builtin_amdgcn_mfma_f32_16x16x32_bf16(af[i], bfq[j], acc[i][j], 0, 0, 0);
      __builtin_amdgcn_s_setprio(0);
      // ---- k-half 1: 24 MFMA ----
#pragma unroll
      for (int i = 0; i < 4; ++i) af[i]  = *(const bf16x8*)(bb + aRd[4 + i]);
#pragma unroll
      for (int j = 0; j < 6; ++j) bfq[j] = *(const bf16x8*)(bb + bRd[6 + j]);
      __builtin_amdgcn_s_setprio(1);
#pragma unroll
      for (int i = 0; i < 4; ++i)
#pragma unroll
        for (int j = 0; j < 6; ++j)
          acc[i][j] = __builtin_amdgcn_mfma_f32_16x16x32_bf16(af[i], bfq[j], acc[i][j], 0, 0, 0);
      __builtin_amdgcn_s_setprio(0);
    }
  }

  // ------ epilogue: 4 chunk-pair rounds (R16), producers idle-sync ------
  const int b   = m0 >> 10;
  const int hl0 = (m0 & 1023) >> 5;
  float bv[6]; int cj[6], pwj[6], prj[6];
#pragma unroll
  for (int j = 0; j < 6; ++j) {
    int o = wn * 96 + j * 16 + lr;         // 0..191 (producers: harmless)
    bv[j]  = bias[n0 + o];
    cj[j]  = o % 3;
    int oq = o / 3;
    pwj[j] = oq & 15;
    prj[j] = oq >> 4;
  }

#pragma unroll
  for (int gp = 0; gp < 4; ++gp) {
    if (w < 4 && wm == 0) {                // chunk gp -> region 0
      float* dst = (float*)(smem);
#pragma unroll
      for (int j = 0; j < 6; ++j)
#pragma unroll
        for (int r = 0; r < 4; ++r) {
          const int tk = lq * 4 + r;
          dst[((cj[j] * 4 + prj[j]) << 8) + (tk << 4) + (pwj[j] ^ (lq << 2))] =
              acc[gp][j][r] + bv[j];
        }
    }
    if (w < 4 && wm == 1) {                // chunk gp+4 -> region 1
      float* dst = (float*)(smem + 16384);
#pragma unroll
      for (int j = 0; j < 6; ++j)
#pragma unroll
        for (int r = 0; r < 4; ++r) {
          const int tk = lq * 4 + r;
          dst[((cj[j] * 4 + prj[j]) << 8) + (tk << 4) + (pwj[j] ^ (lq << 2))] =
              acc[gp][j][r] + bv[j];
        }
    }
    __syncthreads();
    if (tid < 256) {
#pragma unroll
      for (int half2 = 0; half2 < 2; ++half2) {
        const int g  = (half2 << 2) + gp;
        const int hh = hl0 + (g >> 1);
        const float* src = (const float*)(smem + (half2 << 14));
#pragma unroll
        for (int u = 0; u < 3; ++u) {
          const int f   = (u << 8) + tid;
          const int c   = u;
          const int pr  = (f >> 6) & 3;
          const int tk  = (f >> 2) & 15;
          const int pw0 = (f & 3) << 2;
          const int lqw = tk >> 2;
          float4 v = *(const float4*)(src + (((c * 4 + pr) << 8) + (tk << 4)
                                             + (pw0 ^ (lqw << 2))));
          const size_t idx = (((size_t)(b * 3 + c)) << 18)
                           + (size_t)((hh << 4) + (nt << 2) + pr) * 512
                           + ((g & 1) << 8) + (tk << 4) + pw0;
          *(float4*)(out + idx) = v;
        }
      }
    }
    __syncthreads();
  }
}

// ===================== fallback: fused (no workspace) =====================
#define BM 64
#define BK 32
#define NTHR 1024
#define LDS_BYTES 53760

__global__ __launch_bounds__(NTHR, 4)
void fused_kernel(const float* __restrict__ x,
                  const float* __restrict__ lnw,
                  const float* __restrict__ lnb,
                  const float* __restrict__ Wf,
                  const float* __restrict__ bias,
                  float* __restrict__ out)
{
  extern __shared__ char smem[];
  char* AsBase = smem;
  char* BsBase = smem + 4096;
  float* smean = (float*)(smem + 53248);
  float* srstd = smean + BM;

  const int tid = threadIdx.x;
  const int m0  = blockIdx.x * BM;
  const int bb   = m0 >> 10;
  const int h0   = (m0 & 1023) >> 5;

  {
    const int row = tid >> 4;
    const int sub = tid & 15;
    const float4* xr = (const float4*)(x + (size_t)(m0 + row) * DDIM);
    float s = 0.f, ss = 0.f;
#pragma unroll 4
    for (int j = 0; j < 16; ++j) {
      float4 v = xr[sub + (j << 4)];
      s  += v.x + v.y + v.z + v.w;
      ss += v.x * v.x + v.y * v.y + v.z * v.z + v.w * v.w;
    }
#pragma unroll
    for (int off = 1; off < 16; off <<= 1) {
      s  += __shfl_xor(s, off);
      ss += __shfl_xor(ss, off);
    }
    if (sub == 0) {
      float mean = s * (1.f / 1024.f);
      float var  = ss * (1.f / 1024.f) - mean * mean;
      smean[row] = mean;
      srstd[row] = rsqrtf(var + LN_EPS);
    }
  }
  __syncthreads();

  const int arow  = tid >> 4;
  const int acol2 = tid & 15;
  const int aOff  = (m0 + arow) * DDIM + (acol2 << 1);
  const int aDst  = (arow << 6) + ((((acol2 >> 2) ^ ((arow >> 2) & 3)) << 4)) + ((acol2 & 3) << 2);
  const float aMean = smean[arow];
  const float aRstd = srstd[arow];

  int bOffF[6], bDstF[6];
#pragma unroll
  for (int c = 0; c < 6; ++c) {
    int idx = tid + (c << 10);
    int r = idx >> 3, c4 = idx & 7;
    bOffF[c] = r * DDIM + (c4 << 2);
    bDstF[c] = (r << 6) + ((((c4 >> 1) ^ ((r >> 2) & 3)) << 4)) + ((c4 & 1) << 3);
  }

  const int lane = tid & 63;
  const int wid  = tid >> 6;
  const int lr   = lane & 15;
  const int lq   = lane >> 4;
  const int kswz = (lq ^ ((lr >> 2) & 3)) << 4;
  int aRd[4], bRd[3];
#pragma unroll
  for (int i = 0; i < 4; ++i) aRd[i] = (((i << 4) + lr) << 6) + kswz;
#pragma unroll
  for (int j = 0; j < 3; ++j) bRd[j] = ((wid * 48 + (j << 4) + lr) << 6) + kswz;

  float2 aReg, lwReg, lbReg;
  float4 bRegF[6];

  auto loadTile = [&](int tt) {
    const int k0 = tt * BK;
    aReg  = *(const float2*)(x + aOff + k0);
    lwReg = *(const float2*)(lnw + (acol2 << 1) + k0);
    lbReg = *(const float2*)(lnb + (acol2 << 1) + k0);
#pragma unroll
    for (int c = 0; c < 6; ++c)
      bRegF[c] = *(const float4*)(Wf + bOffF[c] + k0);
  };

  auto storeTile = [&]() {
    float hx = (aReg.x - aMean) * aRstd * lwReg.x + lbReg.x;
    float hy = (aReg.y - aMean) * aRstd * lwReg.y + lbReg.y;
    hx = silu_f(hx); hy = silu_f(hy);
    ushort2 ap; ap.x = f2bf(hx); ap.y = f2bf(hy);
    *(ushort2*)(AsBase + aDst) = ap;
#pragma unroll
    for (int c = 0; c < 6; ++c) {
      float4 wv = bRegF[c];
      ushort4 bp; bp.x = f2bf(wv.x); bp.y = f2bf(wv.y); bp.z = f2bf(wv.z); bp.w = f2bf(wv.w);
      *(ushort4*)(BsBase + bDstF[c]) = bp;
    }
  };

  f32x4 acc[4][3];
#pragma unroll
  for (int i = 0; i < 4; ++i)
#pragma unroll
    for (int j = 0; j < 3; ++j)
      acc[i][j] = (f32x4){0.f, 0.f, 0.f, 0.f};

  loadTile(0);
  storeTile();
  __syncthreads();

  for (int t = 0; t < 32; ++t) {
    if (t < 31) loadTile(t + 1);
    bf16x8 af[4], bfr[3];
#pragma unroll
    for (int i = 0; i < 4; ++i) af[i] = *(const bf16x8*)(AsBase + aRd[i]);
#pragma unroll
    for (int j = 0; j < 3; ++j) bfr[j] = *(const bf16x8*)(BsBase + bRd[j]);
#pragma unroll
    for (int i = 0; i < 4; ++i)
#pragma unroll
      for (int j = 0; j < 3; ++j)
        acc[i][j] = __builtin_amdgcn_mfma_f32_16x16x32_bf16(af[i], bfr[j], acc[i][j], 0, 0, 0);
    __syncthreads();
    if (t < 31) storeTile();
    __syncthreads();
  }

  float* ldsF = (float*)smem;
  float bv[3]; int cv[3], phv[3], pwv[3];
#pragma unroll
  for (int j = 0; j < 3; ++j) {
    const int o = wid * 48 + (j << 4) + lr;
    bv[j]  = bias[o];
    cv[j]  = o % 3;
    const int oq = o / 3;
    pwv[j] = oq & 15;
    phv[j] = oq >> 4;
  }

#pragma unroll
  for (int i = 0; i < 4; ++i) {
#pragma unroll
    for (int j = 0; j < 3; ++j) {
#pragma unroll
      for (int r = 0; r < 4; ++r) {
        const int wl  = (lq << 2) + r;
        const int lin = ((cv[j] * 16 + phv[j]) << 8) + (wl << 4) + pwv[j];
        const int dws = lin ^ (cv[j] << 2) ^ (((lin >> 6) & 1) << 4);
        ldsF[dws] = acc[i][j][r] + bv[j];
      }
    }
    __syncthreads();
    const int hq = h0 + (i >> 1);
    const int w0 = (i & 1) << 4;
#pragma unroll
    for (int q = 0; q < 3; ++q) {
      const int g4  = (q << 10) + tid;
      const int dw  = g4 << 2;
      const int run = dw >> 8;
      const int c   = run >> 4;
      const int ph  = run & 15;
      const int wl  = (dw >> 4) & 15;
      const int pw  = dw & 15;
      const int dws = dw ^ (c << 2) ^ (((dw >> 6) & 1) << 4);
      float4 v = *(const float4*)(ldsF + dws);
      const size_t idx = (((size_t)(bb * 3 + c)) << 18)
                       + ((size_t)((hq << 4) + ph) << 9)
                       + ((w0 + wl) << 4) + pw;
      *(float4*)(out + idx) = v;
    }
    __syncthreads();
  }
}

extern "C" void kernel_launch(void* const* d_in, const int* in_sizes, int n_in,
                              void* d_out, int out_size, void* d_ws, size_t ws_size,
                              hipStream_t stream) {
  const float* x    = (const float*)d_in[0];
  const float* lnw  = (const float*)d_in[1];
  const float* lnb  = (const float*)d_in[2];
  const float* W    = (const float*)d_in[3];
  const float* bias = (const float*)d_in[4];
  float* out = (float*)d_out;

  const size_t wbBytes = (size_t)ODIM * DDIM * sizeof(__hip_bfloat16);   // 1.5 MB
  const size_t stBytes = (size_t)M_TOT * sizeof(float);                  // 128 KB
  __hip_bfloat16* Wb  = (__hip_bfloat16*)d_ws;
  float* sm           = (float*)((char*)d_ws + wbBytes);
  float* sr           = (float*)((char*)d_ws + wbBytes + stBytes);
  unsigned* wbpk      = (unsigned*)((char*)d_ws + wbBytes + 2 * stBytes);

  if (ws_size >= wbBytes + 2 * stBytes + DDIM * sizeof(unsigned)) {
    stats_kernel<<<dim3(8192 + 768 + 1), dim3(256), 0, stream>>>(
        x, lnw, lnb, sm, sr, wbpk, (const float4*)W, (ushort4*)Wb);
    gemm_kernel<<<dim3((M_TOT / GBM) * (ODIM / GBN)), dim3(384), 0, stream>>>(
        x, sm, sr, wbpk, Wb, bias, out);
  } else {
    fused_kernel<<<dim3(M_TOT / BM), dim3(NTHR), LDS_BYTES, stream>>>(
        x, lnw, lnb, W, bias, out);
  }
}

// Round 18
// 98.603 us; speedup vs baseline: 2.4197x; 2.4197x over previous
//
#include <hip/hip_runtime.h>
#include <hip/hip_bf16.h>

#define M_TOT 32768
#define DDIM  1024
#define ODIM  768
#define LN_EPS 1e-5f

typedef __attribute__((__ext_vector_type__(8))) short bf16x8;
typedef __attribute__((__ext_vector_type__(4))) float f32x4;

__device__ __forceinline__ unsigned short f2bf(float f) {
  union { __hip_bfloat16 h; unsigned short u; } cv;
  cv.h = __float2bfloat16(f);
  return cv.u;
}

__device__ __forceinline__ float silu_f(float v) {
  return v / (1.f + __expf(-v));
}

// ========== kernel 1: LN+SiLU -> h (bf16), with wconv merged in ==========
// Blocks [0, 8192): LayerNorm+SiLU rows (4 rows/block, HBM-roofline).
// Blocks [8192, 8960): W fp32 -> bf16 conversion (768*1024 elems, 1 f4/thr).
__global__ __launch_bounds__(256)
void ln_silu_kernel(const float* __restrict__ x, const float* __restrict__ lnw,
                    const float* __restrict__ lnb, __hip_bfloat16* __restrict__ h,
                    const float4* __restrict__ Wf, ushort4* __restrict__ Wb)
{
  const int tid  = threadIdx.x;

  if (blockIdx.x >= 8192) {                // ---- wconv part ----
    const int i = (blockIdx.x - 8192) * 256 + tid;   // < 196608
    float4 v = Wf[i];
    ushort4 o;
    o.x = f2bf(v.x); o.y = f2bf(v.y); o.z = f2bf(v.z); o.w = f2bf(v.w);
    Wb[i] = o;
    return;
  }

  const int lane = tid & 63;
  const int wid  = tid >> 6;
  const int row  = blockIdx.x * 4 + wid;

  const float4* xr = (const float4*)(x + (size_t)row * DDIM);
  float4 v[4];
#pragma unroll
  for (int jj = 0; jj < 4; ++jj) v[jj] = xr[lane + 64 * jj];

  float s = 0.f, ss = 0.f;
#pragma unroll
  for (int jj = 0; jj < 4; ++jj) {
    float4 a = v[jj];
    s  += a.x + a.y + a.z + a.w;
    ss += a.x * a.x + a.y * a.y + a.z * a.z + a.w * a.w;
  }
#pragma unroll
  for (int off = 1; off < 64; off <<= 1) {
    s  += __shfl_xor(s, off);
    ss += __shfl_xor(ss, off);
  }
  const float mean = s * (1.f / 1024.f);
  const float rstd = rsqrtf(ss * (1.f / 1024.f) - mean * mean + LN_EPS);

  ushort4* hr = (ushort4*)(h + (size_t)row * DDIM);
#pragma unroll
  for (int jj = 0; jj < 4; ++jj) {
    float4 wv = ((const float4*)lnw)[lane + 64 * jj];
    float4 bv = ((const float4*)lnb)[lane + 64 * jj];
    float4 a  = v[jj];
    float e0 = silu_f((a.x - mean) * rstd * wv.x + bv.x);
    float e1 = silu_f((a.y - mean) * rstd * wv.y + bv.y);
    float e2 = silu_f((a.z - mean) * rstd * wv.z + bv.z);
    float e3 = silu_f((a.w - mean) * rstd * wv.w + bv.w);
    ushort4 o; o.x = f2bf(e0); o.y = f2bf(e1); o.z = f2bf(e2); o.w = f2bf(e3);
    hr[lane + 64 * jj] = o;
  }
}

// ==== kernel 2: GEMM + rearrange (R12/R15 best config; epilogue paired) ====
// BM=128, BN=192, BK=64; 256 thr = 4 waves (2M x 2N), wave C = 64x96.
// Ring-2 LDS = 2 x 40960 = 81920 B -> 2 blocks/CU resident.
// Per tile: VMW(0) [stage(t) landed; covered by tile t-1's compute] -> ONE
// raw barrier -> stage(t+1) -> free-run {frag ds_reads, 48 MFMA in 2
// setprio clusters} with compiler lgkmcnt. Swizzle: chunk ^= row&7.
// Epilogue: 4 chunk-pair rounds (wm0 -> region 0, wm1 -> region 1),
// all-wave write utilization, 8 barriers.
#define GBM 128
#define GBN 192
#define GBK 64
#define ABY  16384   // 128 rows x 128 B
#define BUFB 40960   // + 192 rows x 128 B

__device__ __forceinline__ void gload16(const void* g, void* l) {
  __builtin_amdgcn_global_load_lds(
      (const __attribute__((address_space(1))) unsigned int*)g,
      (__attribute__((address_space(3))) unsigned int*)l, 16, 0, 0);
}

#define VMW(n) asm volatile("s_waitcnt vmcnt(" #n ")" ::: "memory")

__global__ __launch_bounds__(256, 2)
void gemm_kernel(const __hip_bfloat16* __restrict__ h,
                 const __hip_bfloat16* __restrict__ Wb,
                 const float* __restrict__ bias,
                 float* __restrict__ out)
{
  __shared__ char smem[2 * BUFB];          // 81920 B static
  const int tid  = threadIdx.x;
  const int lane = tid & 63;
  const int w    = tid >> 6;

  // bijective XCD swizzle (1024 % 8 == 0); nt fastest -> same-XCD shares A
  const int wg = blockIdx.x;
  const int sv = ((wg & 7) << 7) + (wg >> 3);
  const int mt = sv >> 2, nt = sv & 3;
  const int m0 = mt << 7, n0 = nt * GBN;

  // ---- staging sources (pre-swizzled: 16B chunk ^= row&7; 8 chunks/row) ----
  const __hip_bfloat16* aP[4]; int aD[4];
#pragma unroll
  for (int q = 0; q < 4; ++q) {
    int s = (q << 8) + tid;
    int row = s >> 3, chk = s & 7;
    aP[q] = h + (size_t)(m0 + row) * DDIM + ((chk ^ (row & 7)) << 3);
    aD[q] = s << 4;
  }
  const __hip_bfloat16* bP[6]; int bD[6];
#pragma unroll
  for (int q = 0; q < 6; ++q) {
    int s = (q << 8) + tid;
    int row = s >> 3, chk = s & 7;
    bP[q] = Wb + (size_t)(n0 + row) * DDIM + ((chk ^ (row & 7)) << 3);
    bD[q] = ABY + (s << 4);
  }

  // ---- MFMA fragment LDS read offsets (swizzle-matched) ----
  const int wm = w >> 1, wn = w & 1;       // 2M x 2N
  const int lr = lane & 15, lq = lane >> 4;
  int aRd[8], bRd[12];                     // [kk*4+i], [kk*6+j]
#pragma unroll
  for (int kk = 0; kk < 2; ++kk) {
#pragma unroll
    for (int i = 0; i < 4; ++i) {
      int row = wm * 64 + i * 16 + lr;
      aRd[kk * 4 + i] = row * 128 + ((((kk << 2) | lq) ^ (row & 7)) << 4);
    }
#pragma unroll
    for (int j = 0; j < 6; ++j) {
      int row = wn * 96 + j * 16 + lr;
      bRd[kk * 6 + j] = ABY + row * 128 + ((((kk << 2) | lq) ^ (row & 7)) << 4);
    }
  }

  auto stage = [&](int t) {                // 10 loads/thread
    char* b = smem + (t & 1) * BUFB;
    const int k0 = t << 6;
#pragma unroll
    for (int q = 0; q < 4; ++q) gload16(aP[q] + k0, b + aD[q]);
#pragma unroll
    for (int q = 0; q < 6; ++q) gload16(bP[q] + k0, b + bD[q]);
  };

  f32x4 acc[4][6];
#pragma unroll
  for (int i = 0; i < 4; ++i)
#pragma unroll
    for (int j = 0; j < 6; ++j)
      acc[i][j] = (f32x4){0.f, 0.f, 0.f, 0.f};

  stage(0);

  for (int t = 0; t < 16; ++t) {
    VMW(0);                                // stage(t) landed (drain covered
    __builtin_amdgcn_s_barrier();          //   by tile t-1's compute)
    asm volatile("" ::: "memory");

    const char* bb = smem + (t & 1) * BUFB;
    if (t < 15) stage(t + 1);              // other buffer; its readers retired
                                           // before crossing the barrier
    bf16x8 af[4], bfq[6];
    // ---- k-half 0: 24 MFMA ----
#pragma unroll
    for (int i = 0; i < 4; ++i) af[i]  = *(const bf16x8*)(bb + aRd[i]);
#pragma unroll
    for (int j = 0; j < 6; ++j) bfq[j] = *(const bf16x8*)(bb + bRd[j]);
    __builtin_amdgcn_s_setprio(1);
#pragma unroll
    for (int i = 0; i < 4; ++i)
#pragma unroll
      for (int j = 0; j < 6; ++j)
        acc[i][j] = __builtin_amdgcn_mfma_f32_16x16x32_bf16(af[i], bfq[j], acc[i][j], 0, 0, 0);
    __builtin_amdgcn_s_setprio(0);
    // ---- k-half 1: 24 MFMA ----
#pragma unroll
    for (int i = 0; i < 4; ++i) af[i]  = *(const bf16x8*)(bb + aRd[4 + i]);
#pragma unroll
    for (int j = 0; j < 6; ++j) bfq[j] = *(const bf16x8*)(bb + bRd[6 + j]);
    __builtin_amdgcn_s_setprio(1);
#pragma unroll
    for (int i = 0; i < 4; ++i)
#pragma unroll
      for (int j = 0; j < 6; ++j)
        acc[i][j] = __builtin_amdgcn_mfma_f32_16x16x32_bf16(af[i], bfq[j], acc[i][j], 0, 0, 0);
    __builtin_amdgcn_s_setprio(0);
  }

  // ------ epilogue: 4 chunk-pair rounds, coalesced f4 stores ------
  // Pair (g, g+4): wm0 writes chunk g -> region 0 (byte 0), wm1 writes
  // chunk g+4 -> region 1 (byte 16384). Both < 40960 (buf0); final K-tile
  // (t=15, odd) read frags from buf1, so no write/read race before bar.
  // Chunk buffer [c(3)][pr(4)][tk(16)][pw(16)] f32 = 12 KB; writer spreads
  // banks via pw ^ (lq<<2); reader undoes with lqw = tk>>2.
  const int b   = m0 >> 10;
  const int hl0 = (m0 & 1023) >> 5;
  float bv[6]; int cj[6], pwj[6], prj[6];
#pragma unroll
  for (int j = 0; j < 6; ++j) {
    int o = wn * 96 + j * 16 + lr;         // 0..191
    bv[j]  = bias[n0 + o];
    cj[j]  = o % 3;
    int oq = o / 3;
    pwj[j] = oq & 15;
    prj[j] = oq >> 4;                      // 0..3
  }

#pragma unroll
  for (int gp = 0; gp < 4; ++gp) {
    // write phase: wave group wm writes its chunk (g = wm*4+gp, i_f = gp)
    {
      float* dst = (float*)(smem + (wm << 14));   // region 0 or 1
#pragma unroll
      for (int j = 0; j < 6; ++j)
#pragma unroll
        for (int r = 0; r < 4; ++r) {
          const int tk = lq * 4 + r;
          dst[((cj[j] * 4 + prj[j]) << 8) + (tk << 4) + (pwj[j] ^ (lq << 2))] =
              acc[gp][j][r] + bv[j];
        }
    }
    __syncthreads();
    // read phase: all threads store both chunks of the pair
#pragma unroll
    for (int half = 0; half < 2; ++half) { // chunk g = half*4 + gp
      const int g  = (half << 2) + gp;
      const int hh = hl0 + (g >> 1);
      const float* src = (const float*)(smem + (half << 14));
#pragma unroll
      for (int u = 0; u < 3; ++u) {        // 768 f4 per chunk, 256 thr
        const int f   = (u << 8) + tid;
        const int c   = u;
        const int pr  = (f >> 6) & 3;
        const int tk  = (f >> 2) & 15;
        const int pw0 = (f & 3) << 2;
        const int lqw = tk >> 2;
        float4 v = *(const float4*)(src + (((c * 4 + pr) << 8) + (tk << 4)
                                           + (pw0 ^ (lqw << 2))));
        const size_t idx = (((size_t)(b * 3 + c)) << 18)
                         + (size_t)((hh << 4) + (nt << 2) + pr) * 512
                         + ((g & 1) << 8) + (tk << 4) + pw0;
        *(float4*)(out + idx) = v;
      }
    }
    __syncthreads();
  }
}

// ===================== fallback: fused (no workspace) =====================
#define BM 64
#define BK 32
#define NTHR 1024
#define LDS_BYTES 53760

__global__ __launch_bounds__(NTHR, 4)
void fused_kernel(const float* __restrict__ x,
                  const float* __restrict__ lnw,
                  const float* __restrict__ lnb,
                  const float* __restrict__ Wf,
                  const float* __restrict__ bias,
                  float* __restrict__ out)
{
  extern __shared__ char smem[];
  char* AsBase = smem;
  char* BsBase = smem + 4096;
  float* smean = (float*)(smem + 53248);
  float* srstd = smean + BM;

  const int tid = threadIdx.x;
  const int m0  = blockIdx.x * BM;
  const int bb   = m0 >> 10;
  const int h0   = (m0 & 1023) >> 5;

  {
    const int row = tid >> 4;
    const int sub = tid & 15;
    const float4* xr = (const float4*)(x + (size_t)(m0 + row) * DDIM);
    float s = 0.f, ss = 0.f;
#pragma unroll 4
    for (int j = 0; j < 16; ++j) {
      float4 v = xr[sub + (j << 4)];
      s  += v.x + v.y + v.z + v.w;
      ss += v.x * v.x + v.y * v.y + v.z * v.z + v.w * v.w;
    }
#pragma unroll
    for (int off = 1; off < 16; off <<= 1) {
      s  += __shfl_xor(s, off);
      ss += __shfl_xor(ss, off);
    }
    if (sub == 0) {
      float mean = s * (1.f / 1024.f);
      float var  = ss * (1.f / 1024.f) - mean * mean;
      smean[row] = mean;
      srstd[row] = rsqrtf(var + LN_EPS);
    }
  }
  __syncthreads();

  const int arow  = tid >> 4;
  const int acol2 = tid & 15;
  const int aOff  = (m0 + arow) * DDIM + (acol2 << 1);
  const int aDst  = (arow << 6) + ((((acol2 >> 2) ^ ((arow >> 2) & 3)) << 4)) + ((acol2 & 3) << 2);
  const float aMean = smean[arow];
  const float aRstd = srstd[arow];

  int bOffF[6], bDstF[6];
#pragma unroll
  for (int c = 0; c < 6; ++c) {
    int idx = tid + (c << 10);
    int r = idx >> 3, c4 = idx & 7;
    bOffF[c] = r * DDIM + (c4 << 2);
    bDstF[c] = (r << 6) + ((((c4 >> 1) ^ ((r >> 2) & 3)) << 4)) + ((c4 & 1) << 3);
  }

  const int lane = tid & 63;
  const int wid  = tid >> 6;
  const int lr   = lane & 15;
  const int lq   = lane >> 4;
  const int kswz = (lq ^ ((lr >> 2) & 3)) << 4;
  int aRd[4], bRd[3];
#pragma unroll
  for (int i = 0; i < 4; ++i) aRd[i] = (((i << 4) + lr) << 6) + kswz;
#pragma unroll
  for (int j = 0; j < 3; ++j) bRd[j] = ((wid * 48 + (j << 4) + lr) << 6) + kswz;

  float2 aReg, lwReg, lbReg;
  float4 bRegF[6];

  auto loadTile = [&](int tt) {
    const int k0 = tt * BK;
    aReg  = *(const float2*)(x + aOff + k0);
    lwReg = *(const float2*)(lnw + (acol2 << 1) + k0);
    lbReg = *(const float2*)(lnb + (acol2 << 1) + k0);
#pragma unroll
    for (int c = 0; c < 6; ++c)
      bRegF[c] = *(const float4*)(Wf + bOffF[c] + k0);
  };

  auto storeTile = [&]() {
    float hx = (aReg.x - aMean) * aRstd * lwReg.x + lbReg.x;
    float hy = (aReg.y - aMean) * aRstd * lwReg.y + lbReg.y;
    hx = silu_f(hx); hy = silu_f(hy);
    ushort2 ap; ap.x = f2bf(hx); ap.y = f2bf(hy);
    *(ushort2*)(AsBase + aDst) = ap;
#pragma unroll
    for (int c = 0; c < 6; ++c) {
      float4 wv = bRegF[c];
      ushort4 bp; bp.x = f2bf(wv.x); bp.y = f2bf(wv.y); bp.z = f2bf(wv.z); bp.w = f2bf(wv.w);
      *(ushort4*)(BsBase + bDstF[c]) = bp;
    }
  };

  f32x4 acc[4][3];
#pragma unroll
  for (int i = 0; i < 4; ++i)
#pragma unroll
    for (int j = 0; j < 3; ++j)
      acc[i][j] = (f32x4){0.f, 0.f, 0.f, 0.f};

  loadTile(0);
  storeTile();
  __syncthreads();

  for (int t = 0; t < 32; ++t) {
    if (t < 31) loadTile(t + 1);
    bf16x8 af[4], bfr[3];
#pragma unroll
    for (int i = 0; i < 4; ++i) af[i] = *(const bf16x8*)(AsBase + aRd[i]);
#pragma unroll
    for (int j = 0; j < 3; ++j) bfr[j] = *(const bf16x8*)(BsBase + bRd[j]);
#pragma unroll
    for (int i = 0; i < 4; ++i)
#pragma unroll
      for (int j = 0; j < 3; ++j)
        acc[i][j] = __builtin_amdgcn_mfma_f32_16x16x32_bf16(af[i], bfr[j], acc[i][j], 0, 0, 0);
    __syncthreads();
    if (t < 31) storeTile();
    __syncthreads();
  }

  float* ldsF = (float*)smem;
  float bv[3]; int cv[3], phv[3], pwv[3];
#pragma unroll
  for (int j = 0; j < 3; ++j) {
    const int o = wid * 48 + (j << 4) + lr;
    bv[j]  = bias[o];
    cv[j]  = o % 3;
    const int oq = o / 3;
    pwv[j] = oq & 15;
    phv[j] = oq >> 4;
  }

#pragma unroll
  for (int i = 0; i < 4; ++i) {
#pragma unroll
    for (int j = 0; j < 3; ++j) {
#pragma unroll
      for (int r = 0; r < 4; ++r) {
        const int wl  = (lq << 2) + r;
        const int lin = ((cv[j] * 16 + phv[j]) << 8) + (wl << 4) + pwv[j];
        const int dws = lin ^ (cv[j] << 2) ^ (((lin >> 6) & 1) << 4);
        ldsF[dws] = acc[i][j][r] + bv[j];
      }
    }
    __syncthreads();
    const int hq = h0 + (i >> 1);
    const int w0 = (i & 1) << 4;
#pragma unroll
    for (int q = 0; q < 3; ++q) {
      const int g4  = (q << 10) + tid;
      const int dw  = g4 << 2;
      const int run = dw >> 8;
      const int c   = run >> 4;
      const int ph  = run & 15;
      const int wl  = (dw >> 4) & 15;
      const int pw  = dw & 15;
      const int dws = dw ^ (c << 2) ^ (((dw >> 6) & 1) << 4);
      float4 v = *(const float4*)(ldsF + dws);
      const size_t idx = (((size_t)(bb * 3 + c)) << 18)
                       + ((size_t)((hq << 4) + ph) << 9)
                       + ((w0 + wl) << 4) + pw;
      *(float4*)(out + idx) = v;
    }
    __syncthreads();
  }
}

extern "C" void kernel_launch(void* const* d_in, const int* in_sizes, int n_in,
                              void* d_out, int out_size, void* d_ws, size_t ws_size,
                              hipStream_t stream) {
  const float* x    = (const float*)d_in[0];
  const float* lnw  = (const float*)d_in[1];
  const float* lnb  = (const float*)d_in[2];
  const float* W    = (const float*)d_in[3];
  const float* bias = (const float*)d_in[4];
  float* out = (float*)d_out;

  const size_t wbBytes = (size_t)ODIM * DDIM * sizeof(__hip_bfloat16);   // 1.5 MB
  const size_t hBytes  = (size_t)M_TOT * DDIM * sizeof(__hip_bfloat16);  // 64 MB
  __hip_bfloat16* Wb = (__hip_bfloat16*)d_ws;
  __hip_bfloat16* hb = (__hip_bfloat16*)((char*)d_ws + wbBytes);

  if (ws_size >= wbBytes + hBytes) {
    // ln_silu (8192 blocks) + merged wconv (768 blocks)
    ln_silu_kernel<<<dim3(8192 + 768), dim3(256), 0, stream>>>(
        x, lnw, lnb, hb, (const float4*)W, (ushort4*)Wb);
    gemm_kernel<<<dim3((M_TOT / GBM) * (ODIM / GBN)), dim3(256), 0, stream>>>(hb, Wb, bias, out);
  } else {
    fused_kernel<<<dim3(M_TOT / BM), dim3(NTHR), LDS_BYTES, stream>>>(
        x, lnw, lnb, W, bias, out);
  }
}

// Round 20
// 88.186 us; speedup vs baseline: 2.7055x; 1.1181x over previous
//
#include <hip/hip_runtime.h>
#include <hip/hip_bf16.h>

#define M_TOT 32768
#define DDIM  1024
#define ODIM  768
#define LN_EPS 1e-5f

typedef __attribute__((__ext_vector_type__(8))) short bf16x8;
typedef __attribute__((__ext_vector_type__(4))) float f32x4;

__device__ __forceinline__ unsigned short f2bf(float f) {
  union { __hip_bfloat16 h; unsigned short u; } cv;
  cv.h = __float2bfloat16(f);
  return cv.u;
}

__device__ __forceinline__ float silu_f(float v) {
  return v / (1.f + __expf(-v));
}

// ========== kernel 1: LN+SiLU -> h (bf16), with wconv merged in ==========
// Blocks [0, 8192): LayerNorm+SiLU rows (4 rows/block, HBM-roofline ~89%).
// Blocks [8192, 8960): W fp32 -> bf16 conversion (768*1024 elems, 1 f4/thr).
__global__ __launch_bounds__(256)
void ln_silu_kernel(const float* __restrict__ x, const float* __restrict__ lnw,
                    const float* __restrict__ lnb, __hip_bfloat16* __restrict__ h,
                    const float4* __restrict__ Wf, ushort4* __restrict__ Wb)
{
  const int tid  = threadIdx.x;

  if (blockIdx.x >= 8192) {                // ---- wconv part ----
    const int i = (blockIdx.x - 8192) * 256 + tid;   // < 196608
    float4 v = Wf[i];
    ushort4 o;
    o.x = f2bf(v.x); o.y = f2bf(v.y); o.z = f2bf(v.z); o.w = f2bf(v.w);
    Wb[i] = o;
    return;
  }

  const int lane = tid & 63;
  const int wid  = tid >> 6;
  const int row  = blockIdx.x * 4 + wid;

  const float4* xr = (const float4*)(x + (size_t)row * DDIM);
  float4 v[4];
#pragma unroll
  for (int jj = 0; jj < 4; ++jj) v[jj] = xr[lane + 64 * jj];

  float s = 0.f, ss = 0.f;
#pragma unroll
  for (int jj = 0; jj < 4; ++jj) {
    float4 a = v[jj];
    s  += a.x + a.y + a.z + a.w;
    ss += a.x * a.x + a.y * a.y + a.z * a.z + a.w * a.w;
  }
#pragma unroll
  for (int off = 1; off < 64; off <<= 1) {
    s  += __shfl_xor(s, off);
    ss += __shfl_xor(ss, off);
  }
  const float mean = s * (1.f / 1024.f);
  const float rstd = rsqrtf(ss * (1.f / 1024.f) - mean * mean + LN_EPS);

  ushort4* hr = (ushort4*)(h + (size_t)row * DDIM);
#pragma unroll
  for (int jj = 0; jj < 4; ++jj) {
    float4 wv = ((const float4*)lnw)[lane + 64 * jj];
    float4 bv = ((const float4*)lnb)[lane + 64 * jj];
    float4 a  = v[jj];
    float e0 = silu_f((a.x - mean) * rstd * wv.x + bv.x);
    float e1 = silu_f((a.y - mean) * rstd * wv.y + bv.y);
    float e2 = silu_f((a.z - mean) * rstd * wv.z + bv.z);
    float e3 = silu_f((a.w - mean) * rstd * wv.w + bv.w);
    ushort4 o; o.x = f2bf(e0); o.y = f2bf(e1); o.z = f2bf(e2); o.w = f2bf(e3);
    hr[lane + 64 * jj] = o;
  }
}

// ==== kernel 2: GEMM + rearrange (R15 config; -setprio, +nontemporal out) ==
// BM=128, BN=192, BK=64; 256 thr = 4 waves (2M x 2N), wave C = 64x96.
// Ring-2 LDS = 2 x 40960 = 81920 B -> 2 blocks/CU resident.
// Per tile: VMW(0) [stage(t) landed; covered by tile t-1's compute] -> ONE
// raw barrier -> stage(t+1) -> free-run {frag ds_reads, 48 MFMA} with
// compiler lgkmcnt. Swizzle: chunk ^= row&7.
// Deltas under test: (1) setprio REMOVED (T5 null-to-negative on
// non-phase-split loops, m190). (2) out stores NON-TEMPORAL via f32x4
// (clang vector type -- HIP float4 struct is rejected by the builtin);
// out is write-once and was churning the 4 MB/XCD L2 lines holding h/Wb.
#define GBM 128
#define GBN 192
#define GBK 64
#define ABY  16384   // 128 rows x 128 B
#define BUFB 40960   // + 192 rows x 128 B

__device__ __forceinline__ void gload16(const void* g, void* l) {
  __builtin_amdgcn_global_load_lds(
      (const __attribute__((address_space(1))) unsigned int*)g,
      (__attribute__((address_space(3))) unsigned int*)l, 16, 0, 0);
}

#define VMW(n) asm volatile("s_waitcnt vmcnt(" #n ")" ::: "memory")

__global__ __launch_bounds__(256, 2)
void gemm_kernel(const __hip_bfloat16* __restrict__ h,
                 const __hip_bfloat16* __restrict__ Wb,
                 const float* __restrict__ bias,
                 float* __restrict__ out)
{
  __shared__ char smem[2 * BUFB];          // 81920 B static
  const int tid  = threadIdx.x;
  const int lane = tid & 63;
  const int w    = tid >> 6;

  // bijective XCD swizzle (1024 % 8 == 0); nt fastest -> same-XCD shares A
  const int wg = blockIdx.x;
  const int sv = ((wg & 7) << 7) + (wg >> 3);
  const int mt = sv >> 2, nt = sv & 3;
  const int m0 = mt << 7, n0 = nt * GBN;

  // ---- staging sources (pre-swizzled: 16B chunk ^= row&7; 8 chunks/row) ----
  const __hip_bfloat16* aP[4]; int aD[4];
#pragma unroll
  for (int q = 0; q < 4; ++q) {
    int s = (q << 8) + tid;
    int row = s >> 3, chk = s & 7;
    aP[q] = h + (size_t)(m0 + row) * DDIM + ((chk ^ (row & 7)) << 3);
    aD[q] = s << 4;
  }
  const __hip_bfloat16* bP[6]; int bD[6];
#pragma unroll
  for (int q = 0; q < 6; ++q) {
    int s = (q << 8) + tid;
    int row = s >> 3, chk = s & 7;
    bP[q] = Wb + (size_t)(n0 + row) * DDIM + ((chk ^ (row & 7)) << 3);
    bD[q] = ABY + (s << 4);
  }

  // ---- MFMA fragment LDS read offsets (swizzle-matched) ----
  const int wm = w >> 1, wn = w & 1;       // 2M x 2N
  const int lr = lane & 15, lq = lane >> 4;
  int aRd[8], bRd[12];                     // [kk*4+i], [kk*6+j]
#pragma unroll
  for (int kk = 0; kk < 2; ++kk) {
#pragma unroll
    for (int i = 0; i < 4; ++i) {
      int row = wm * 64 + i * 16 + lr;
      aRd[kk * 4 + i] = row * 128 + ((((kk << 2) | lq) ^ (row & 7)) << 4);
    }
#pragma unroll
    for (int j = 0; j < 6; ++j) {
      int row = wn * 96 + j * 16 + lr;
      bRd[kk * 6 + j] = ABY + row * 128 + ((((kk << 2) | lq) ^ (row & 7)) << 4);
    }
  }

  auto stage = [&](int t) {                // 10 loads/thread
    char* b = smem + (t & 1) * BUFB;
    const int k0 = t << 6;
#pragma unroll
    for (int q = 0; q < 4; ++q) gload16(aP[q] + k0, b + aD[q]);
#pragma unroll
    for (int q = 0; q < 6; ++q) gload16(bP[q] + k0, b + bD[q]);
  };

  f32x4 acc[4][6];
#pragma unroll
  for (int i = 0; i < 4; ++i)
#pragma unroll
    for (int j = 0; j < 6; ++j)
      acc[i][j] = (f32x4){0.f, 0.f, 0.f, 0.f};

  stage(0);

  for (int t = 0; t < 16; ++t) {
    VMW(0);                                // stage(t) landed (drain covered
    __builtin_amdgcn_s_barrier();          //   by tile t-1's compute)
    asm volatile("" ::: "memory");

    const char* bb = smem + (t & 1) * BUFB;
    if (t < 15) stage(t + 1);              // other buffer; its readers retired
                                           // before crossing the barrier
    bf16x8 af[4], bfq[6];
    // ---- k-half 0: 24 MFMA ----
#pragma unroll
    for (int i = 0; i < 4; ++i) af[i]  = *(const bf16x8*)(bb + aRd[i]);
#pragma unroll
    for (int j = 0; j < 6; ++j) bfq[j] = *(const bf16x8*)(bb + bRd[j]);
#pragma unroll
    for (int i = 0; i < 4; ++i)
#pragma unroll
      for (int j = 0; j < 6; ++j)
        acc[i][j] = __builtin_amdgcn_mfma_f32_16x16x32_bf16(af[i], bfq[j], acc[i][j], 0, 0, 0);
    // ---- k-half 1: 24 MFMA ----
#pragma unroll
    for (int i = 0; i < 4; ++i) af[i]  = *(const bf16x8*)(bb + aRd[4 + i]);
#pragma unroll
    for (int j = 0; j < 6; ++j) bfq[j] = *(const bf16x8*)(bb + bRd[6 + j]);
#pragma unroll
    for (int i = 0; i < 4; ++i)
#pragma unroll
      for (int j = 0; j < 6; ++j)
        acc[i][j] = __builtin_amdgcn_mfma_f32_16x16x32_bf16(af[i], bfq[j], acc[i][j], 0, 0, 0);
  }

  // ------ epilogue: 4 chunk-pair rounds, nontemporal coalesced f4 stores ----
  // Pair (g, g+4): wm0 writes chunk g -> region 0 (byte 0), wm1 writes
  // chunk g+4 -> region 1 (byte 16384). Both < 40960 (buf0); final K-tile
  // (t=15, odd) read frags from buf1, so no write/read race before bar.
  // Chunk buffer [c(3)][pr(4)][tk(16)][pw(16)] f32 = 12 KB; writer spreads
  // banks via pw ^ (lq<<2); reader undoes with lqw = tk>>2.
  const int b   = m0 >> 10;
  const int hl0 = (m0 & 1023) >> 5;
  float bv[6]; int cj[6], pwj[6], prj[6];
#pragma unroll
  for (int j = 0; j < 6; ++j) {
    int o = wn * 96 + j * 16 + lr;         // 0..191
    bv[j]  = bias[n0 + o];
    cj[j]  = o % 3;
    int oq = o / 3;
    pwj[j] = oq & 15;
    prj[j] = oq >> 4;                      // 0..3
  }

#pragma unroll
  for (int gp = 0; gp < 4; ++gp) {
    // write phase: wave group wm writes its chunk (g = wm*4+gp, i_f = gp)
    {
      float* dst = (float*)(smem + (wm << 14));   // region 0 or 1
#pragma unroll
      for (int j = 0; j < 6; ++j)
#pragma unroll
        for (int r = 0; r < 4; ++r) {
          const int tk = lq * 4 + r;
          dst[((cj[j] * 4 + prj[j]) << 8) + (tk << 4) + (pwj[j] ^ (lq << 2))] =
              acc[gp][j][r] + bv[j];
        }
    }
    __syncthreads();
    // read phase: all threads store both chunks of the pair
#pragma unroll
    for (int half = 0; half < 2; ++half) { // chunk g = half*4 + gp
      const int g  = (half << 2) + gp;
      const int hh = hl0 + (g >> 1);
      const float* src = (const float*)(smem + (half << 14));
#pragma unroll
      for (int u = 0; u < 3; ++u) {        // 768 f4 per chunk, 256 thr
        const int f   = (u << 8) + tid;
        const int c   = u;
        const int pr  = (f >> 6) & 3;
        const int tk  = (f >> 2) & 15;
        const int pw0 = (f & 3) << 2;
        const int lqw = tk >> 2;
        f32x4 v = *(const f32x4*)(src + (((c * 4 + pr) << 8) + (tk << 4)
                                         + (pw0 ^ (lqw << 2))));
        const size_t idx = (((size_t)(b * 3 + c)) << 18)
                         + (size_t)((hh << 4) + (nt << 2) + pr) * 512
                         + ((g & 1) << 8) + (tk << 4) + pw0;
        __builtin_nontemporal_store(v, (f32x4*)(out + idx));
      }
    }
    __syncthreads();
  }
}

// ===================== fallback: fused (no workspace) =====================
#define BM 64
#define BK 32
#define NTHR 1024
#define LDS_BYTES 53760

__global__ __launch_bounds__(NTHR, 4)
void fused_kernel(const float* __restrict__ x,
                  const float* __restrict__ lnw,
                  const float* __restrict__ lnb,
                  const float* __restrict__ Wf,
                  const float* __restrict__ bias,
                  float* __restrict__ out)
{
  extern __shared__ char smem[];
  char* AsBase = smem;
  char* BsBase = smem + 4096;
  float* smean = (float*)(smem + 53248);
  float* srstd = smean + BM;

  const int tid = threadIdx.x;
  const int m0  = blockIdx.x * BM;
  const int bb   = m0 >> 10;
  const int h0   = (m0 & 1023) >> 5;

  {
    const int row = tid >> 4;
    const int sub = tid & 15;
    const float4* xr = (const float4*)(x + (size_t)(m0 + row) * DDIM);
    float s = 0.f, ss = 0.f;
#pragma unroll 4
    for (int j = 0; j < 16; ++j) {
      float4 v = xr[sub + (j << 4)];
      s  += v.x + v.y + v.z + v.w;
      ss += v.x * v.x + v.y * v.y + v.z * v.z + v.w * v.w;
    }
#pragma unroll
    for (int off = 1; off < 16; off <<= 1) {
      s  += __shfl_xor(s, off);
      ss += __shfl_xor(ss, off);
    }
    if (sub == 0) {
      float mean = s * (1.f / 1024.f);
      float var  = ss * (1.f / 1024.f) - mean * mean;
      smean[row] = mean;
      srstd[row] = rsqrtf(var + LN_EPS);
    }
  }
  __syncthreads();

  const int arow  = tid >> 4;
  const int acol2 = tid & 15;
  const int aOff  = (m0 + arow) * DDIM + (acol2 << 1);
  const int aDst  = (arow << 6) + ((((acol2 >> 2) ^ ((arow >> 2) & 3)) << 4)) + ((acol2 & 3) << 2);
  const float aMean = smean[arow];
  const float aRstd = srstd[arow];

  int bOffF[6], bDstF[6];
#pragma unroll
  for (int c = 0; c < 6; ++c) {
    int idx = tid + (c << 10);
    int r = idx >> 3, c4 = idx & 7;
    bOffF[c] = r * DDIM + (c4 << 2);
    bDstF[c] = (r << 6) + ((((c4 >> 1) ^ ((r >> 2) & 3)) << 4)) + ((c4 & 1) << 3);
  }

  const int lane = tid & 63;
  const int wid  = tid >> 6;
  const int lr   = lane & 15;
  const int lq   = lane >> 4;
  const int kswz = (lq ^ ((lr >> 2) & 3)) << 4;
  int aRd[4], bRd[3];
#pragma unroll
  for (int i = 0; i < 4; ++i) aRd[i] = (((i << 4) + lr) << 6) + kswz;
#pragma unroll
  for (int j = 0; j < 3; ++j) bRd[j] = ((wid * 48 + (j << 4) + lr) << 6) + kswz;

  float2 aReg, lwReg, lbReg;
  float4 bRegF[6];

  auto loadTile = [&](int tt) {
    const int k0 = tt * BK;
    aReg  = *(const float2*)(x + aOff + k0);
    lwReg = *(const float2*)(lnw + (acol2 << 1) + k0);
    lbReg = *(const float2*)(lnb + (acol2 << 1) + k0);
#pragma unroll
    for (int c = 0; c < 6; ++c)
      bRegF[c] = *(const float4*)(Wf + bOffF[c] + k0);
  };

  auto storeTile = [&]() {
    float hx = (aReg.x - aMean) * aRstd * lwReg.x + lbReg.x;
    float hy = (aReg.y - aMean) * aRstd * lwReg.y + lbReg.y;
    hx = silu_f(hx); hy = silu_f(hy);
    ushort2 ap; ap.x = f2bf(hx); ap.y = f2bf(hy);
    *(ushort2*)(AsBase + aDst) = ap;
#pragma unroll
    for (int c = 0; c < 6; ++c) {
      float4 wv = bRegF[c];
      ushort4 bp; bp.x = f2bf(wv.x); bp.y = f2bf(wv.y); bp.z = f2bf(wv.z); bp.w = f2bf(wv.w);
      *(ushort4*)(BsBase + bDstF[c]) = bp;
    }
  };

  f32x4 acc[4][3];
#pragma unroll
  for (int i = 0; i < 4; ++i)
#pragma unroll
    for (int j = 0; j < 3; ++j)
      acc[i][j] = (f32x4){0.f, 0.f, 0.f, 0.f};

  loadTile(0);
  storeTile();
  __syncthreads();

  for (int t = 0; t < 32; ++t) {
    if (t < 31) loadTile(t + 1);
    bf16x8 af[4], bfr[3];
#pragma unroll
    for (int i = 0; i < 4; ++i) af[i] = *(const bf16x8*)(AsBase + aRd[i]);
#pragma unroll
    for (int j = 0; j < 3; ++j) bfr[j] = *(const bf16x8*)(BsBase + bRd[j]);
#pragma unroll
    for (int i = 0; i < 4; ++i)
#pragma unroll
      for (int j = 0; j < 3; ++j)
        acc[i][j] = __builtin_amdgcn_mfma_f32_16x16x32_bf16(af[i], bfr[j], acc[i][j], 0, 0, 0);
    __syncthreads();
    if (t < 31) storeTile();
    __syncthreads();
  }

  float* ldsF = (float*)smem;
  float bv[3]; int cv[3], phv[3], pwv[3];
#pragma unroll
  for (int j = 0; j < 3; ++j) {
    const int o = wid * 48 + (j << 4) + lr;
    bv[j]  = bias[o];
    cv[j]  = o % 3;
    const int oq = o / 3;
    pwv[j] = oq & 15;
    phv[j] = oq >> 4;
  }

#pragma unroll
  for (int i = 0; i < 4; ++i) {
#pragma unroll
    for (int j = 0; j < 3; ++j) {
#pragma unroll
      for (int r = 0; r < 4; ++r) {
        const int wl  = (lq << 2) + r;
        const int lin = ((cv[j] * 16 + phv[j]) << 8) + (wl << 4) + pwv[j];
        const int dws = lin ^ (cv[j] << 2) ^ (((lin >> 6) & 1) << 4);
        ldsF[dws] = acc[i][j][r] + bv[j];
      }
    }
    __syncthreads();
    const int hq = h0 + (i >> 1);
    const int w0 = (i & 1) << 4;
#pragma unroll
    for (int q = 0; q < 3; ++q) {
      const int g4  = (q << 10) + tid;
      const int dw  = g4 << 2;
      const int run = dw >> 8;
      const int c   = run >> 4;
      const int ph  = run & 15;
      const int wl  = (dw >> 4) & 15;
      const int pw  = dw & 15;
      const int dws = dw ^ (c << 2) ^ (((dw >> 6) & 1) << 4);
      float4 v = *(const float4*)(ldsF + dws);
      const size_t idx = (((size_t)(bb * 3 + c)) << 18)
                       + ((size_t)((hq << 4) + ph) << 9)
                       + ((w0 + wl) << 4) + pw;
      *(float4*)(out + idx) = v;
    }
    __syncthreads();
  }
}

extern "C" void kernel_launch(void* const* d_in, const int* in_sizes, int n_in,
                              void* d_out, int out_size, void* d_ws, size_t ws_size,
                              hipStream_t stream) {
  const float* x    = (const float*)d_in[0];
  const float* lnw  = (const float*)d_in[1];
  const float* lnb  = (const float*)d_in[2];
  const float* W    = (const float*)d_in[3];
  const float* bias = (const float*)d_in[4];
  float* out = (float*)d_out;

  const size_t wbBytes = (size_t)ODIM * DDIM * sizeof(__hip_bfloat16);   // 1.5 MB
  const size_t hBytes  = (size_t)M_TOT * DDIM * sizeof(__hip_bfloat16);  // 64 MB
  __hip_bfloat16* Wb = (__hip_bfloat16*)d_ws;
  __hip_bfloat16* hb = (__hip_bfloat16*)((char*)d_ws + wbBytes);

  if (ws_size >= wbBytes + hBytes) {
    // ln_silu (8192 blocks) + merged wconv (768 blocks)
    ln_silu_kernel<<<dim3(8192 + 768), dim3(256), 0, stream>>>(
        x, lnw, lnb, hb, (const float4*)W, (ushort4*)Wb);
    gemm_kernel<<<dim3((M_TOT / GBM) * (ODIM / GBN)), dim3(256), 0, stream>>>(hb, Wb, bias, out);
  } else {
    fused_kernel<<<dim3(M_TOT / BM), dim3(NTHR), LDS_BYTES, stream>>>(
        x, lnw, lnb, W, bias, out);
  }
}